// Round 1
// baseline (24.059 us; speedup 1.0000x reference)
//
#include <hip/hip_runtime.h>

// LIF forward scan: x [T=32, B=128, N=4096] f32 -> spikes [T, B, N] f32.
// Recurrence per neuron (independent across B*N):
//   v += (x_t - v) / 2;  s = (v - 1 > 0);  v *= (1 - s)
// One thread owns 4 consecutive neurons (float4 loads/stores), carries
// 4 states in registers, loops t serially (fully unrolled).

#define LIF_T 32

__global__ __launch_bounds__(256) void lif_fwd_kernel(const float* __restrict__ x,
                                                      float* __restrict__ out,
                                                      int bn) {
    const int i = (blockIdx.x * blockDim.x + threadIdx.x) * 4;
    if (i >= bn) return;

    float v0 = 0.f, v1 = 0.f, v2 = 0.f, v3 = 0.f;

    #pragma unroll
    for (int t = 0; t < LIF_T; ++t) {
        const size_t off = (size_t)t * (size_t)bn + (size_t)i;
        const float4 xv = *reinterpret_cast<const float4*>(x + off);

        // v = v + (x - v) * 0.5  (matches reference: v + (x_t - v)/tau, tau=2.0)
        v0 = v0 + (xv.x - v0) * 0.5f;
        v1 = v1 + (xv.y - v1) * 0.5f;
        v2 = v2 + (xv.z - v2) * 0.5f;
        v3 = v3 + (xv.w - v3) * 0.5f;

        float4 s;
        s.x = (v0 - 1.0f > 0.0f) ? 1.0f : 0.0f;
        s.y = (v1 - 1.0f > 0.0f) ? 1.0f : 0.0f;
        s.z = (v2 - 1.0f > 0.0f) ? 1.0f : 0.0f;
        s.w = (v3 - 1.0f > 0.0f) ? 1.0f : 0.0f;

        // v *= (1 - s): reset to exactly 0 on spike
        v0 = (s.x != 0.0f) ? 0.0f : v0;
        v1 = (s.y != 0.0f) ? 0.0f : v1;
        v2 = (s.z != 0.0f) ? 0.0f : v2;
        v3 = (s.w != 0.0f) ? 0.0f : v3;

        *reinterpret_cast<float4*>(out + off) = s;
    }
}

extern "C" void kernel_launch(void* const* d_in, const int* in_sizes, int n_in,
                              void* d_out, int out_size, void* d_ws, size_t ws_size,
                              hipStream_t stream) {
    const float* x = (const float*)d_in[0];
    float* out = (float*)d_out;

    const int total = in_sizes[0];          // T * B * N = 16,777,216
    const int bn = total / LIF_T;           // B * N = 524,288

    const int threads = 256;
    const int elems_per_thread = 4;
    const int nthreads = bn / elems_per_thread;          // 131,072
    const int blocks = (nthreads + threads - 1) / threads; // 512

    lif_fwd_kernel<<<blocks, threads, 0, stream>>>(x, out, bn);
}